// Round 9
// baseline (231.861 us; speedup 1.0000x reference)
//
#include <hip/hip_runtime.h>
#include <math.h>

#define AS1 __attribute__((address_space(1)))
#define AS3 __attribute__((address_space(3)))

typedef __attribute__((ext_vector_type(8))) short short8;
typedef __attribute__((ext_vector_type(4))) float f32x4;

#define WAITV(n) asm volatile("s_waitcnt vmcnt(" #n ")" ::: "memory")
#define BARRIER() asm volatile("s_barrier" ::: "memory")

static __device__ __forceinline__ unsigned short f2bf(float f) {
    unsigned u = __float_as_uint(f);
    unsigned r = (u + 0x7fffu + ((u >> 16) & 1u)) >> 16;
    return (unsigned short)r;
}
static __device__ __forceinline__ float bf2f(unsigned short u) {
    return __uint_as_float(((unsigned)u) << 16);
}

// ---------------- f32 -> bf16 convert (vectorized x4) ----------------
__global__ __launch_bounds__(256) void cvt_f32_bf16(const float* __restrict__ src,
                                                    unsigned short* __restrict__ dst,
                                                    int n4) {
    int i = blockIdx.x * 256 + threadIdx.x;
    int stride = gridDim.x * 256;
    for (; i < n4; i += stride) {
        float4 v = ((const float4*)src)[i];
        ushort4 o;
        o.x = f2bf(v.x); o.y = f2bf(v.y); o.z = f2bf(v.z); o.w = f2bf(v.w);
        ((ushort4*)dst)[i] = o;
    }
}

// extract ts (cols 0..127 of ssm_p, row stride 160) -> dense bf16 1024x128
__global__ __launch_bounds__(256) void cvt_ts(const float* __restrict__ ssmp,
                                              unsigned short* __restrict__ ts) {
    int i = blockIdx.x * 256 + threadIdx.x;   // < 32768
    int t = i >> 5, c4 = (i & 31) * 4;
    float4 v = *(const float4*)&ssmp[t * 160 + c4];
    ushort4 o;
    o.x = f2bf(v.x); o.y = f2bf(v.y); o.z = f2bf(v.z); o.w = f2bf(v.w);
    *(ushort4*)&ts[t * 128 + c4] = o;
}

// ------- depthwise causal conv (K=4, bf16 in) + bias + silu -> hc bf16 -------
__global__ __launch_bounds__(256) void conv_silu(const unsigned short* __restrict__ h,
                                                 const float* __restrict__ cw,
                                                 const float* __restrict__ cb,
                                                 unsigned short* __restrict__ hc_bf) {
    int idx = blockIdx.x * 256 + threadIdx.x;   // < 1024*4096
    int d = idx & 4095, t = idx >> 12;
    float acc = cb[d];
    float4 w = *(const float4*)&cw[d * 4];
    const float* wp = (const float*)&w;
#pragma unroll
    for (int k = 0; k < 4; ++k) {
        int tt = t + k - 3;
        if (tt >= 0) acc += bf2f(h[tt * 4096 + d]) * wp[k];
    }
    float s = acc / (1.f + __expf(-acc));   // silu
    hc_bf[idx] = f2bf(s);
}

// ---------------- reduce 4 split-K partials -> out ----------------
__global__ __launch_bounds__(256) void reduce4(const float* __restrict__ pA,
                                               const float* __restrict__ pB,
                                               float* __restrict__ out, int n4) {
    int i = blockIdx.x * 256 + threadIdx.x;
    int stride = gridDim.x * 256;
    const size_t MN4 = (size_t)1024 * 2048 / 4;
    for (; i < n4; i += stride) {
        float4 a = ((const float4*)pA)[i];
        float4 b = ((const float4*)pA)[i + MN4];
        float4 c = ((const float4*)pB)[i];
        float4 d = ((const float4*)pB)[i + MN4];
        float4 o;
        o.x = (a.x + b.x) + (c.x + d.x);
        o.y = (a.y + b.y) + (c.y + d.y);
        o.z = (a.z + b.z) + (c.z + d.z);
        o.w = (a.w + b.w) + (c.w + d.w);
        ((float4*)out)[i] = o;
    }
}

// ======== pipelined bf16 MFMA GEMM: C(M,N)=A(M,K)@B(N,K)^T ========
// BM=128, BN=256, BK=64. 256 threads = 4 waves (2M x 2N), wave tile 64x128
// (fat tile: 6 B/lane LDS-read per MFMA; per-CU LDS reads 48KB/K-tile vs
// MFMA 1242 cyc -> MFMA-dominant). ONE wave/SIMD: all ds_read<->MFMA overlap
// is intra-wave software pipelining by the compiler (no cross-wave phase
// lock possible). 3-buf LDS (144KB), prefetch depth 2, counted vmcnt
// (12/tile), one s_barrier per K-tile. XOR-swizzled LDS via pre-swizzled
// global source (linear dest, rule 21). XCD-bijective swizzle. M = 1024.
enum { P_GATE = 0, P_PART = 1 };

template <int EPI>
__global__ __launch_bounds__(256, 1)
void gemm8p(const short* __restrict__ A, const short* __restrict__ B,
            void* __restrict__ C0v, void* __restrict__ C1v,
            int N, int K, int kchunk) {
    __shared__ short lds[3 * 24576];   // per buf: A 128x64 (8192) + B 256x64 (16384)

    const int tid = threadIdx.x;
    const int wv = tid >> 6, ln = tid & 63;
    const int lr = ln & 15, kg = ln >> 4;
    const int wm = wv >> 1, wn = wv & 1;

    const int nwg = gridDim.x;
    const int bid = blockIdx.x;
    const int swz = (bid & 7) * (nwg >> 3) + (bid >> 3);   // nwg % 8 == 0
    const int by = swz & 7, bx = swz >> 3;
    const int m0 = by * 128;
    const int n0 = bx * 256;
    const int kbeg = blockIdx.z * kchunk;
    const int NT = kchunk >> 6;

    f32x4 acc[4][8];
#pragma unroll
    for (int mi = 0; mi < 4; ++mi)
#pragma unroll
        for (int ni = 0; ni < 8; ++ni) acc[mi][ni] = (f32x4){0.f, 0.f, 0.f, 0.f};

    const short* Abase = A + (size_t)m0 * K + kbeg;
    const short* Bbase = B + (size_t)n0 * K + kbeg;

// 12 global_load_lds per thread per K-tile (A: 4 passes, B: 8 passes).
// source column pre-swizzled so LDS[row][byte j] = Global[row][byte j ^ ((row&7)<<4)]
#define STAGE(kt, b)                                                          \
    {                                                                         \
        short* lbase = &lds[(b) * 24576];                                     \
        _Pragma("unroll")                                                     \
        for (int r = 0; r < 4; ++r) {                                         \
            int c = r * 256 + tid;                                            \
            int row = c >> 3, cb8 = (c & 7) << 4;                             \
            int scb = cb8 ^ ((row & 7) << 4);                                 \
            const short* src = Abase + (size_t)row * K + (kt) * 64 + (scb >> 1); \
            short* dst = lbase + (r * 256 + wv * 64) * 8;                     \
            __builtin_amdgcn_global_load_lds((const AS1 void*)src,            \
                                             (AS3 void*)dst, 16, 0, 0);       \
        }                                                                     \
        _Pragma("unroll")                                                     \
        for (int r = 0; r < 8; ++r) {                                         \
            int c = r * 256 + tid;                                            \
            int row = c >> 3, cb8 = (c & 7) << 4;                             \
            int scb = cb8 ^ ((row & 7) << 4);                                 \
            const short* src = Bbase + (size_t)row * K + (kt) * 64 + (scb >> 1); \
            short* dst = lbase + 8192 + (r * 256 + wv * 64) * 8;              \
            __builtin_amdgcn_global_load_lds((const AS1 void*)src,            \
                                             (AS3 void*)dst, 16, 0, 0);       \
        }                                                                     \
    }
#define RD_A(dst, mi, ks)                                                     \
    { int row = wm * 64 + (mi) * 16 + lr;                                     \
      int col = ((ks) * 32 + kg * 8) ^ ((row & 7) << 3);                      \
      dst = *(const short8*)&la[row * 64 + col]; }
#define RD_B(dst, ni, ks)                                                     \
    { int row = wn * 128 + (ni) * 16 + lr;                                    \
      int col = ((ks) * 32 + kg * 8) ^ ((row & 7) << 3);                      \
      dst = *(const short8*)&lb[row * 64 + col]; }
#define MFMA8(mi, a)                                                          \
    acc[mi][0] = __builtin_amdgcn_mfma_f32_16x16x32_bf16(a, vb0, acc[mi][0], 0, 0, 0); \
    acc[mi][1] = __builtin_amdgcn_mfma_f32_16x16x32_bf16(a, vb1, acc[mi][1], 0, 0, 0); \
    acc[mi][2] = __builtin_amdgcn_mfma_f32_16x16x32_bf16(a, vb2, acc[mi][2], 0, 0, 0); \
    acc[mi][3] = __builtin_amdgcn_mfma_f32_16x16x32_bf16(a, vb3, acc[mi][3], 0, 0, 0); \
    acc[mi][4] = __builtin_amdgcn_mfma_f32_16x16x32_bf16(a, vb4, acc[mi][4], 0, 0, 0); \
    acc[mi][5] = __builtin_amdgcn_mfma_f32_16x16x32_bf16(a, vb5, acc[mi][5], 0, 0, 0); \
    acc[mi][6] = __builtin_amdgcn_mfma_f32_16x16x32_bf16(a, vb6, acc[mi][6], 0, 0, 0); \
    acc[mi][7] = __builtin_amdgcn_mfma_f32_16x16x32_bf16(a, vb7, acc[mi][7], 0, 0, 0);

    // prologue: fully stage tiles 0 and 1
    STAGE(0, 0);
    STAGE(1, 1);

    for (int kt = 0; kt < NT; ++kt) {
        const int b = kt % 3;
        // drain exactly tile kt's 12 loads; deeper tiles stay in flight
        int ahead = NT - 1 - kt;
        if (ahead > 2) ahead = 2;
        if (ahead == 2) { WAITV(24); } else if (ahead == 1) { WAITV(12); } else { WAITV(0); }
        BARRIER();   // buf b staged; all waves finished tile kt-1
        // prefetch tile kt+2 into buf (kt+2)%3 == (kt-1)%3 (safe post-barrier)
        if (kt + 2 < NT) STAGE(kt + 2, (kt + 2) % 3);

        const short* la = &lds[b * 24576];
        const short* lb = la + 8192;
        short8 va0, va1, va2, va3, vb0, vb1, vb2, vb3, vb4, vb5, vb6, vb7;
        // ks = 0 : 12 ds_read + 32 MFMA
        RD_B(vb0, 0, 0); RD_B(vb1, 1, 0); RD_B(vb2, 2, 0); RD_B(vb3, 3, 0);
        RD_B(vb4, 4, 0); RD_B(vb5, 5, 0); RD_B(vb6, 6, 0); RD_B(vb7, 7, 0);
        RD_A(va0, 0, 0); RD_A(va1, 1, 0); RD_A(va2, 2, 0); RD_A(va3, 3, 0);
        __builtin_amdgcn_s_setprio(1);
        MFMA8(0, va0); MFMA8(1, va1); MFMA8(2, va2); MFMA8(3, va3);
        __builtin_amdgcn_s_setprio(0);
        // ks = 1 : 12 ds_read + 32 MFMA (compiler pipelines under ks=0 MFMAs)
        RD_B(vb0, 0, 1); RD_B(vb1, 1, 1); RD_B(vb2, 2, 1); RD_B(vb3, 3, 1);
        RD_B(vb4, 4, 1); RD_B(vb5, 5, 1); RD_B(vb6, 6, 1); RD_B(vb7, 7, 1);
        RD_A(va0, 0, 1); RD_A(va1, 1, 1); RD_A(va2, 2, 1); RD_A(va3, 3, 1);
        __builtin_amdgcn_s_setprio(1);
        MFMA8(0, va0); MFMA8(1, va1); MFMA8(2, va2); MFMA8(3, va3);
        __builtin_amdgcn_s_setprio(0);
    }
#undef STAGE
#undef RD_A
#undef RD_B
#undef MFMA8

#pragma unroll
    for (int mi = 0; mi < 4; ++mi) {
        int crow0 = m0 + wm * 64 + mi * 16 + kg * 4;
#pragma unroll
        for (int ni = 0; ni < 8; ++ni) {
            int ccol = n0 + wn * 128 + ni * 16 + lr;
#pragma unroll
            for (int i = 0; i < 4; ++i) {
                float v = acc[mi][ni][i];
                size_t crow = (size_t)(crow0 + i);
                if constexpr (EPI == P_GATE) {
                    // h (bf16) | silu(gate) (bf16)
                    if (ccol < 4096) ((unsigned short*)C0v)[crow * 4096 + ccol] = f2bf(v);
                    else {
                        float s = v / (1.f + __expf(-v));
                        ((unsigned short*)C1v)[crow * 4096 + (ccol - 4096)] = f2bf(s);
                    }
                } else {
                    // split-K partial plain stores: z=0,1 -> C0; z=2,3 -> C1
                    float* P = (float*)(blockIdx.z < 2 ? C0v : C1v) +
                               (size_t)(blockIdx.z & 1) * 1024 * 2048;
                    P[crow * N + ccol] = v;
                }
            }
        }
    }
}

// ---------------- 2-phase bf16 MFMA GEMM (GEMM2/3) ----------------
enum { EPI_PLAIN = 0, EPI_SPLIT = 1, EPI_ATOMIC = 2, EPI_SOFTPLUS = 3 };

template <int BM, int EPI>
__global__ __launch_bounds__(256)
void gemm_bt(const short* __restrict__ A, const short* __restrict__ B,
             float* __restrict__ C, float* __restrict__ C2,
             const float* __restrict__ bias,
             int M, int N, int K, int ldc, int kcLen) {
    __shared__ short A_lds[BM * 32];
    __shared__ short B_lds[128 * 32];
    const int tid = threadIdx.x;
    const int wv = tid >> 6, ln = tid & 63;
    const int lr = ln & 15, kg = ln >> 4;
    const int m0 = blockIdx.y * BM;
    const int n0 = blockIdx.x * 128;
    const int kbeg = blockIdx.z * kcLen;
    const int kend = kbeg + kcLen;
    const int wm = wv >> 1, wn = wv & 1;
    constexpr int MR = BM / 32;

    f32x4 acc[MR][4];
#pragma unroll
    for (int mi = 0; mi < MR; ++mi)
#pragma unroll
        for (int ni = 0; ni < 4; ++ni) acc[mi][ni] = (f32x4){0.f, 0.f, 0.f, 0.f};

    const int arow = tid >> 2;
    const int kq8 = (tid & 3) * 8;

    for (int k0 = kbeg; k0 < kend; k0 += 32) {
#pragma unroll
        for (int r = 0; r < BM / 64; ++r) {
            const short* srcA = A + (size_t)(m0 + r * 64 + arow) * K + (k0 + kq8);
            short* dstA = &A_lds[(r * 64 + wv * 16) * 32];
            __builtin_amdgcn_global_load_lds((const AS1 void*)srcA, (AS3 void*)dstA, 16, 0, 0);
        }
#pragma unroll
        for (int r = 0; r < 2; ++r) {
            int brow = n0 + r * 64 + arow;
            if (brow > N - 1) brow = N - 1;
            const short* srcB = B + (size_t)brow * K + (k0 + kq8);
            short* dstB = &B_lds[(r * 64 + wv * 16) * 32];
            __builtin_amdgcn_global_load_lds((const AS1 void*)srcB, (AS3 void*)dstB, 16, 0, 0);
        }
        __syncthreads();

        short8 av[MR], bv[4];
#pragma unroll
        for (int mi = 0; mi < MR; ++mi)
            av[mi] = *(const short8*)&A_lds[(wm * (BM / 2) + mi * 16 + lr) * 32 + kg * 8];
#pragma unroll
        for (int ni = 0; ni < 4; ++ni)
            bv[ni] = *(const short8*)&B_lds[(wn * 64 + ni * 16 + lr) * 32 + kg * 8];
#pragma unroll
        for (int mi = 0; mi < MR; ++mi)
#pragma unroll
            for (int ni = 0; ni < 4; ++ni)
                acc[mi][ni] = __builtin_amdgcn_mfma_f32_16x16x32_bf16(av[mi], bv[ni], acc[mi][ni], 0, 0, 0);
        __syncthreads();
    }

#pragma unroll
    for (int mi = 0; mi < MR; ++mi) {
        int crow0 = m0 + wm * (BM / 2) + mi * 16 + kg * 4;
#pragma unroll
        for (int ni = 0; ni < 4; ++ni) {
            int ccol = n0 + wn * 64 + ni * 16 + lr;
#pragma unroll
            for (int i = 0; i < 4; ++i) {
                float v = acc[mi][ni][i];
                size_t crow = (size_t)(crow0 + i);
                if constexpr (EPI == EPI_PLAIN) {
                    C[crow * ldc + ccol] = v;
                } else if constexpr (EPI == EPI_SPLIT) {
                    if (ccol < 4096) C[crow * 4096 + ccol] = v;
                    else C2[crow * 4096 + (ccol - 4096)] = v;
                } else if constexpr (EPI == EPI_ATOMIC) {
                    if (ccol < N) atomicAdd(&C[crow * ldc + ccol], v);
                } else {   // EPI_SOFTPLUS: bf16 softplus(v + bias[n]) -> dt
                    float x = v + bias[ccol];
                    float sp = fmaxf(x, 0.f) + log1pf(__expf(-fabsf(x)));
                    ((unsigned short*)C)[crow * ldc + ccol] = f2bf(sp);
                }
            }
        }
    }
}

// ================= chunked selective scan (bf16 dt/hc/gate) =================
#define CLEN 16
#define NCH 64

__global__ __launch_bounds__(256)
void scan_p1(const unsigned short* __restrict__ dt, const unsigned short* __restrict__ hc,
             const float* __restrict__ ssmp, const float* __restrict__ A_log,
             float* __restrict__ Sbuf, float* __restrict__ dtsum) {
    const int tid = threadIdx.x;
    const int c = blockIdx.x & (NCH - 1);
    const int db = blockIdx.x >> 6;
    const int d = db * 256 + tid;
    const int t0 = c * CLEN;

    float Ac[16];
#pragma unroll
    for (int i = 0; i < 4; ++i) {
        float4 v = *(const float4*)&A_log[d * 16 + i * 4];
        Ac[i*4+0] = -__expf(v.x); Ac[i*4+1] = -__expf(v.y);
        Ac[i*4+2] = -__expf(v.z); Ac[i*4+3] = -__expf(v.w);
    }

    __shared__ float sB[CLEN][16];
    sB[tid >> 4][tid & 15] = ssmp[(t0 + (tid >> 4)) * 160 + 128 + (tid & 15)];
    __syncthreads();

    float st[16];
#pragma unroll
    for (int n = 0; n < 16; ++n) st[n] = 0.f;
    float ds = 0.f;

    for (int tt = 0; tt < CLEN; ++tt) {
        size_t g = (size_t)(t0 + tt) * 4096 + d;
        float dtv = bf2f(dt[g]);
        float hcv = bf2f(hc[g]);
        float du = dtv * hcv;
        ds += dtv;
#pragma unroll
        for (int n = 0; n < 16; ++n) {
            float dA = __expf(dtv * Ac[n]);
            st[n] = fmaf(dA, st[n], du * sB[tt][n]);
        }
    }

    float* o = Sbuf + ((size_t)c * 4096 + d) * 16;
#pragma unroll
    for (int i = 0; i < 4; ++i)
        *(float4*)&o[i * 4] = make_float4(st[i*4], st[i*4+1], st[i*4+2], st[i*4+3]);
    dtsum[c * 4096 + d] = ds;
}

__global__ __launch_bounds__(256)
void scan_p2(const float* __restrict__ A_log, const float* __restrict__ dtsum,
             float* __restrict__ S) {
    const int idx = blockIdx.x * 256 + threadIdx.x;   // (d,n), 65536
    const int d = idx >> 4;
    const float Ac = -__expf(A_log[idx]);

    float sl[NCH], Pv[NCH];
#pragma unroll
    for (int c = 0; c < NCH; ++c) sl[c] = S[(size_t)c * 65536 + idx];
#pragma unroll
    for (int c = 0; c < NCH; ++c) Pv[c] = __expf(Ac * dtsum[c * 4096 + d]);

    float s = 0.f;
#pragma unroll
    for (int c = 0; c < NCH; ++c) {
        S[(size_t)c * 65536 + idx] = s;
        s = fmaf(Pv[c], s, sl[c]);
    }
}

__global__ __launch_bounds__(256)
void scan_p3(const unsigned short* __restrict__ dt, const unsigned short* __restrict__ hc,
             const float* __restrict__ ssmp, const float* __restrict__ A_log,
             const float* __restrict__ Dp, const unsigned short* __restrict__ gate,
             const float* __restrict__ Sinit, unsigned short* __restrict__ y_bf) {
    const int tid = threadIdx.x;
    const int c = blockIdx.x & (NCH - 1);
    const int db = blockIdx.x >> 6;
    const int d = db * 256 + tid;
    const int t0 = c * CLEN;

    float Ac[16];
#pragma unroll
    for (int i = 0; i < 4; ++i) {
        float4 v = *(const float4*)&A_log[d * 16 + i * 4];
        Ac[i*4+0] = -__expf(v.x); Ac[i*4+1] = -__expf(v.y);
        Ac[i*4+2] = -__expf(v.z); Ac[i*4+3] = -__expf(v.w);
    }
    const float Dcoef = Dp[d];

    __shared__ float sB[CLEN][16], sC[CLEN][16];
    {
        int tt = tid >> 4, nn = tid & 15;
        sB[tt][nn] = ssmp[(t0 + tt) * 160 + 128 + nn];
        sC[tt][nn] = ssmp[(t0 + tt) * 160 + 144 + nn];
    }
    __syncthreads();

    float st[16];
    {
        const float* si = Sinit + ((size_t)c * 4096 + d) * 16;
#pragma unroll
        for (int i = 0; i < 4; ++i) {
            float4 v = *(const float4*)&si[i * 4];
            st[i*4] = v.x; st[i*4+1] = v.y; st[i*4+2] = v.z; st[i*4+3] = v.w;
        }
    }

    for (int tt = 0; tt < CLEN; ++tt) {
        size_t g = (size_t)(t0 + tt) * 4096 + d;
        float dtv = bf2f(dt[g]);
        float hcv = bf2f(hc[g]);
        float du = dtv * hcv;
        float p[16];
#pragma unroll
        for (int n = 0; n < 16; ++n) {
            float dA = __expf(dtv * Ac[n]);
            st[n] = fmaf(dA, st[n], du * sB[tt][n]);
            p[n] = st[n] * sC[tt][n];
        }
#pragma unroll
        for (int n = 0; n < 8; ++n) p[n] += p[n + 8];
#pragma unroll
        for (int n = 0; n < 4; ++n) p[n] += p[n + 4];
        p[0] += p[2]; p[1] += p[3];
        float csum = p[0] + p[1];
        float gv = bf2f(gate[g]);   // already silu'd
        float yv = (csum + hcv * Dcoef) * gv;
        y_bf[g] = f2bf(yv);
    }
}

// ---------------- launch ----------------
extern "C" void kernel_launch(void* const* d_in, const int* in_sizes, int n_in,
                              void* d_out, int out_size, void* d_ws, size_t ws_size,
                              hipStream_t stream) {
    (void)in_sizes; (void)n_in; (void)out_size; (void)ws_size;
    const float* hidden = (const float*)d_in[0];
    const float* W_in   = (const float*)d_in[1];
    const float* conv_w = (const float*)d_in[2];
    const float* conv_b = (const float*)d_in[3];
    const float* W_x    = (const float*)d_in[4];
    const float* W_dt   = (const float*)d_in[5];
    const float* b_dt   = (const float*)d_in[6];
    const float* A_log  = (const float*)d_in[7];
    const float* D_p    = (const float*)d_in[8];
    const float* W_out  = (const float*)d_in[9];
    float* out = (float*)d_out;

    char* w = (char*)d_ws;
    unsigned short* hid_bf = (unsigned short*)w;  w += (size_t)1024 * 2048 * 2;
    unsigned short* Wbig   = (unsigned short*)w;  w += (size_t)8192 * 2048 * 2;
    float* h_buf           = (float*)w;           w += (size_t)1024 * 4096 * 4;  // h bf16 (first 8MB); later GEMM4 partials z2,z3
    unsigned short* gate_bf= (unsigned short*)w;  w += (size_t)1024 * 4096 * 2;  // silu(gate) bf16
    unsigned short* hc_bf  = (unsigned short*)w;  w += (size_t)1024 * 4096 * 2;
    unsigned short* dt_bf  = (unsigned short*)w;  w += (size_t)1024 * 4096 * 2;
    float* ssmp            = (float*)w;           w += (size_t)1024 * 160 * 4;
    unsigned short* ts_bf  = (unsigned short*)w;  w += (size_t)1024 * 128 * 2;
    unsigned short* Wx_bf  = (unsigned short*)w;  w += (size_t)160 * 4096 * 2;
    unsigned short* Wdt_bf = (unsigned short*)w;  w += (size_t)4096 * 128 * 2;
    unsigned short* y_bf   = (unsigned short*)w;  w += (size_t)1024 * 4096 * 2;
    float* Sbuf            = (float*)w;           w += (size_t)NCH * 4096 * 16 * 4; // scan states; later GEMM4 partials z0,z1
    float* dtsum           = (float*)w;           w += (size_t)NCH * 4096 * 4;

    hipMemsetAsync(ssmp, 0, (size_t)1024 * 160 * 4, stream);   // GEMM2 atomic target

    cvt_f32_bf16<<<2048, 256, 0, stream>>>(hidden, hid_bf, 1024 * 2048 / 4);
    cvt_f32_bf16<<<4096, 256, 0, stream>>>(W_in, Wbig, 8192 * 2048 / 4);
    cvt_f32_bf16<<<640, 256, 0, stream>>>(W_x, Wx_bf, 160 * 4096 / 4);
    cvt_f32_bf16<<<512, 256, 0, stream>>>(W_dt, Wdt_bf, 4096 * 128 / 4);

    // GEMM1: proj = hidden @ W_in^T -> h (bf16) | silu(gate) (bf16)
    gemm8p<P_GATE><<<dim3(256, 1, 1), 256, 0, stream>>>(
        (const short*)hid_bf, (const short*)Wbig, h_buf, gate_bf, 8192, 2048, 2048);

    conv_silu<<<16384, 256, 0, stream>>>((const unsigned short*)h_buf, conv_w, conv_b, hc_bf);

    cvt_f32_bf16<<<2048, 256, 0, stream>>>(W_out, Wbig, 2048 * 4096 / 4);

    gemm_bt<128, EPI_ATOMIC><<<dim3(2, 8, 16), 256, 0, stream>>>(
        (const short*)hc_bf, (const short*)Wx_bf, ssmp, nullptr, nullptr,
        1024, 160, 4096, 160, 256);

    cvt_ts<<<128, 256, 0, stream>>>(ssmp, ts_bf);

    // GEMM3: dt = softplus(ts @ W_dt^T + b_dt) -> bf16
    gemm_bt<128, EPI_SOFTPLUS><<<dim3(32, 8, 1), 256, 0, stream>>>(
        (const short*)ts_bf, (const short*)Wdt_bf, (float*)dt_bf, nullptr, b_dt,
        1024, 4096, 128, 4096, 128);

    scan_p1<<<NCH * 16, 256, 0, stream>>>(dt_bf, hc_bf, ssmp, A_log, Sbuf, dtsum);
    scan_p2<<<256, 256, 0, stream>>>(A_log, dtsum, Sbuf);
    scan_p3<<<NCH * 16, 256, 0, stream>>>(dt_bf, hc_bf, ssmp, A_log, D_p, gate_bf, Sbuf, y_bf);

    // GEMM4: out = y @ W_out^T — split-K x4, plain-store partials into dead
    // Sbuf (z=0,1) / h_buf (z=2,3), then vectorized reduce.
    gemm8p<P_PART><<<dim3(64, 1, 4), 256, 0, stream>>>(
        (const short*)y_bf, (const short*)Wbig, Sbuf, h_buf, 2048, 4096, 1024);
    reduce4<<<2048, 256, 0, stream>>>(Sbuf, h_buf, out, 1024 * 2048 / 4);
}

// Round 10
// 227.764 us; speedup vs baseline: 1.0180x; 1.0180x over previous
//
#include <hip/hip_runtime.h>
#include <math.h>

#define AS1 __attribute__((address_space(1)))
#define AS3 __attribute__((address_space(3)))

typedef __attribute__((ext_vector_type(8))) short short8;
typedef __attribute__((ext_vector_type(8))) unsigned short ushort8_t;
typedef __attribute__((ext_vector_type(4))) float f32x4;

#define WAITV(n) asm volatile("s_waitcnt vmcnt(" #n ")" ::: "memory")
#define BARRIER() asm volatile("s_barrier" ::: "memory")

static __device__ __forceinline__ unsigned short f2bf(float f) {
    unsigned u = __float_as_uint(f);
    unsigned r = (u + 0x7fffu + ((u >> 16) & 1u)) >> 16;
    return (unsigned short)r;
}
static __device__ __forceinline__ float bf2f(unsigned short u) {
    return __uint_as_float(((unsigned)u) << 16);
}

// ---------------- f32 -> bf16 convert (vectorized x4) ----------------
__global__ __launch_bounds__(256) void cvt_f32_bf16(const float* __restrict__ src,
                                                    unsigned short* __restrict__ dst,
                                                    int n4) {
    int i = blockIdx.x * 256 + threadIdx.x;
    int stride = gridDim.x * 256;
    for (; i < n4; i += stride) {
        float4 v = ((const float4*)src)[i];
        ushort4 o;
        o.x = f2bf(v.x); o.y = f2bf(v.y); o.z = f2bf(v.z); o.w = f2bf(v.w);
        ((ushort4*)dst)[i] = o;
    }
}

// extract ts (cols 0..127 of ssm_p, row stride 160) -> dense bf16 1024x128
__global__ __launch_bounds__(256) void cvt_ts(const float* __restrict__ ssmp,
                                              unsigned short* __restrict__ ts) {
    int i = blockIdx.x * 256 + threadIdx.x;   // < 32768
    int t = i >> 5, c4 = (i & 31) * 4;
    float4 v = *(const float4*)&ssmp[t * 160 + c4];
    ushort4 o;
    o.x = f2bf(v.x); o.y = f2bf(v.y); o.z = f2bf(v.z); o.w = f2bf(v.w);
    *(ushort4*)&ts[t * 128 + c4] = o;
}

// ------- depthwise causal conv (K=4, bf16 in) + bias + silu -> hc bf16 -------
__global__ __launch_bounds__(256) void conv_silu(const unsigned short* __restrict__ h,
                                                 const float* __restrict__ cw,
                                                 const float* __restrict__ cb,
                                                 unsigned short* __restrict__ hc_bf) {
    int idx = blockIdx.x * 256 + threadIdx.x;   // < 1024*4096
    int d = idx & 4095, t = idx >> 12;
    float acc = cb[d];
    float4 w = *(const float4*)&cw[d * 4];
    const float* wp = (const float*)&w;
#pragma unroll
    for (int k = 0; k < 4; ++k) {
        int tt = t + k - 3;
        if (tt >= 0) acc += bf2f(h[tt * 4096 + d]) * wp[k];
    }
    float s = acc / (1.f + __expf(-acc));   // silu
    hc_bf[idx] = f2bf(s);
}

// ---- reduce 2 bf16 split-K partials (1024x8192) -> h bf16 | silu(gate) bf16 ----
__global__ __launch_bounds__(256) void reduce2(const unsigned short* __restrict__ P,
                                               unsigned short* __restrict__ h_bf,
                                               unsigned short* __restrict__ gate_bf) {
    const int NCHK = 1024 * 8192 / 8;
    int i = blockIdx.x * 256 + threadIdx.x;
    int stride = gridDim.x * 256;
    for (; i < NCHK; i += stride) {
        ushort8_t a = ((const ushort8_t*)P)[i];
        ushort8_t b = ((const ushort8_t*)P)[i + NCHK];
        int e0 = i * 8;
        int row = e0 >> 13, col = e0 & 8191;
        ushort8_t o;
        if (col < 4096) {
#pragma unroll
            for (int j = 0; j < 8; ++j) o[j] = f2bf(bf2f(a[j]) + bf2f(b[j]));
            ((ushort8_t*)h_bf)[(row * 4096 + col) >> 3] = o;
        } else {
#pragma unroll
            for (int j = 0; j < 8; ++j) {
                float v = bf2f(a[j]) + bf2f(b[j]);
                o[j] = f2bf(v / (1.f + __expf(-v)));
            }
            ((ushort8_t*)gate_bf)[(row * 4096 + (col - 4096)) >> 3] = o;
        }
    }
}

// ---- reduce 8 bf16 split-K partials (1024x2048 each) -> f32 out ----
__global__ __launch_bounds__(256) void reduce8(const unsigned short* __restrict__ P,
                                               float* __restrict__ out) {
    const int NCHK = 1024 * 2048 / 4;
    int i = blockIdx.x * 256 + threadIdx.x;
    int stride = gridDim.x * 256;
    for (; i < NCHK; i += stride) {
        float4 s = make_float4(0.f, 0.f, 0.f, 0.f);
#pragma unroll
        for (int z = 0; z < 8; ++z) {
            ushort4 v = ((const ushort4*)(P + (size_t)z * 1024 * 2048))[i];
            s.x += bf2f(v.x); s.y += bf2f(v.y); s.z += bf2f(v.z); s.w += bf2f(v.w);
        }
        ((float4*)out)[i] = s;
    }
}

// ======== 256x256 quadrant-phase bf16 MFMA GEMM: C = A(M,K) @ B(N,K)^T ========
// BM=BN=256, BK=32. 512 threads = 8 waves (2M x 4N), wave tile 128x64
// (m201 geometry: per-CU LDS reads 96KB/K-tile (~750cyc) < MFMA (~1024cyc/
// SIMD-pair) -> MFMA-dominant). 3-buffer LDS (96KB), prefetch depth 2,
// counted vmcnt(4) (never 0 mid-loop), 2 quadrant-phases per K-tile
// {12 ds_read, 2 staging passes, setprio, 16 MFMA, barrier}. At BK=32 the
// natural [256][32] row-major layout is bank-conflict-free for BOTH the
// linear global_load_lds writes and the fragment ds_read_b128 pattern
// (8 accesses/bank = the 1KB floor) -> NO swizzle needed. XCD-bijective
// block swizzle. Split-K partials stored bf16, reduced by reduce2/reduce8.
// M fixed = 1024 (4 tile rows).
__global__ __launch_bounds__(512, 2)
void gemm256p(const short* __restrict__ A, const short* __restrict__ B,
              unsigned short* __restrict__ Pbase,
              int N, int K, int kchunk) {
    __shared__ short lds[3 * 16384];   // per buf: A [256][32] (8192) + B [256][32]

    const int tid = threadIdx.x;
    const int wv = tid >> 6, ln = tid & 63;
    const int lr = ln & 15, kg = ln >> 4;
    const int wm = wv >> 2, wn = wv & 3;      // 2M x 4N

    const int nwg = gridDim.x;                 // multiple of 8
    const int bid = blockIdx.x;
    const int swz = (bid & 7) * (nwg >> 3) + (bid >> 3);
    const int by = swz & 3, bx = swz >> 2;     // M/256 = 4 always
    const int m0 = by * 256, n0 = bx * 256;
    const int kbeg = blockIdx.z * kchunk;
    const int NT = kchunk >> 5;                // BK = 32

    f32x4 acc[8][4];
#pragma unroll
    for (int mi = 0; mi < 8; ++mi)
#pragma unroll
        for (int ni = 0; ni < 4; ++ni) acc[mi][ni] = (f32x4){0.f, 0.f, 0.f, 0.f};

    const short* Abase = A + (size_t)m0 * K + kbeg;
    const short* Bbase = B + (size_t)n0 * K + kbeg;

// one staging pass: 512 threads x 16B = 128 rows of [256][32] bf16 (linear LDS dest)
#define STG(gbase, ldsoff, kt, b, pass)                                       \
    {                                                                         \
        int c = (pass) * 512 + tid;                                           \
        int row = c >> 2, ch = (c & 3) * 8;                                   \
        const short* src = (gbase) + (size_t)row * K + (kt) * 32 + ch;        \
        short* dst = &lds[(b) * 16384 + (ldsoff) + ((pass) * 512 + wv * 64) * 8]; \
        __builtin_amdgcn_global_load_lds((const AS1 void*)src,                \
                                         (AS3 void*)dst, 16, 0, 0);           \
    }
#define STAGE_A(kt, b) { STG(Abase, 0, kt, b, 0); STG(Abase, 0, kt, b, 1); }
#define STAGE_B(kt, b) { STG(Bbase, 8192, kt, b, 0); STG(Bbase, 8192, kt, b, 1); }
#define RD_A(dst, mi)                                                         \
    { int row = wm * 128 + (mi) * 16 + lr;                                    \
      dst = *(const short8*)&la[row * 32 + kg * 8]; }
#define RD_B(dst, ni)                                                         \
    { int row = wn * 64 + (ni) * 16 + lr;                                     \
      dst = *(const short8*)&lb[row * 32 + kg * 8]; }
#define MFMA4(mi, a)                                                          \
    acc[mi][0] = __builtin_amdgcn_mfma_f32_16x16x32_bf16(a, vb0, acc[mi][0], 0, 0, 0); \
    acc[mi][1] = __builtin_amdgcn_mfma_f32_16x16x32_bf16(a, vb1, acc[mi][1], 0, 0, 0); \
    acc[mi][2] = __builtin_amdgcn_mfma_f32_16x16x32_bf16(a, vb2, acc[mi][2], 0, 0, 0); \
    acc[mi][3] = __builtin_amdgcn_mfma_f32_16x16x32_bf16(a, vb3, acc[mi][3], 0, 0, 0);

    // prologue: stage tiles 0 and 1 fully (4 loads each)
    STAGE_A(0, 0); STAGE_B(0, 0);
    STAGE_A(1, 1); STAGE_B(1, 1);

    int b = 0;
    for (int kt = 0; kt < NT; ++kt) {
        // drain exactly tile kt's 4 loads; tile kt+1's 4 stay in flight
        if (kt + 1 < NT) { WAITV(4); } else { WAITV(0); }
        BARRIER();   // tile kt staged & visible; all waves finished tile kt-1
        int bn = b + 2; if (bn >= 3) bn -= 3;    // == (kt-1)%3, freed by barrier
        if (kt + 2 < NT) STAGE_A(kt + 2, bn);

        const short* la = &lds[b * 16384];
        const short* lb = la + 8192;
        short8 va0, va1, va2, va3, vb0, vb1, vb2, vb3;
        // ---- phase 0: quadrant rows 0-63 of wave tile ----
        RD_B(vb0, 0); RD_B(vb1, 1); RD_B(vb2, 2); RD_B(vb3, 3);
        RD_A(va0, 0); RD_A(va1, 1); RD_A(va2, 2); RD_A(va3, 3);
        __builtin_amdgcn_s_setprio(1);
        MFMA4(0, va0); MFMA4(1, va1); MFMA4(2, va2); MFMA4(3, va3);
        __builtin_amdgcn_s_setprio(0);
        BARRIER();   // phase-lock: early waves' next reads drain under late MFMAs
        if (kt + 2 < NT) STAGE_B(kt + 2, bn);
        // ---- phase 1: quadrant rows 64-127 (B frags reused) ----
        RD_A(va0, 4); RD_A(va1, 5); RD_A(va2, 6); RD_A(va3, 7);
        __builtin_amdgcn_s_setprio(1);
        MFMA4(4, va0); MFMA4(5, va1); MFMA4(6, va2); MFMA4(7, va3);
        __builtin_amdgcn_s_setprio(0);
        b = (b + 1 == 3) ? 0 : b + 1;
    }
#undef STG
#undef STAGE_A
#undef STAGE_B
#undef RD_A
#undef RD_B
#undef MFMA4

    // epilogue: bf16 split-K partial, region z = blockIdx.z
    unsigned short* P = Pbase + (size_t)blockIdx.z * 1024 * N;
#pragma unroll
    for (int mi = 0; mi < 8; ++mi) {
        int crow0 = m0 + wm * 128 + mi * 16 + kg * 4;
#pragma unroll
        for (int ni = 0; ni < 4; ++ni) {
            int ccol = n0 + wn * 64 + ni * 16 + lr;
#pragma unroll
            for (int i = 0; i < 4; ++i)
                P[(size_t)(crow0 + i) * N + ccol] = f2bf(acc[mi][ni][i]);
        }
    }
}

// ---------------- 2-phase bf16 MFMA GEMM (GEMM2/3) ----------------
enum { EPI_PLAIN = 0, EPI_SPLIT = 1, EPI_ATOMIC = 2, EPI_SOFTPLUS = 3 };

template <int BM, int EPI>
__global__ __launch_bounds__(256)
void gemm_bt(const short* __restrict__ A, const short* __restrict__ B,
             float* __restrict__ C, float* __restrict__ C2,
             const float* __restrict__ bias,
             int M, int N, int K, int ldc, int kcLen) {
    __shared__ short A_lds[BM * 32];
    __shared__ short B_lds[128 * 32];
    const int tid = threadIdx.x;
    const int wv = tid >> 6, ln = tid & 63;
    const int lr = ln & 15, kg = ln >> 4;
    const int m0 = blockIdx.y * BM;
    const int n0 = blockIdx.x * 128;
    const int kbeg = blockIdx.z * kcLen;
    const int kend = kbeg + kcLen;
    const int wm = wv >> 1, wn = wv & 1;
    constexpr int MR = BM / 32;

    f32x4 acc[MR][4];
#pragma unroll
    for (int mi = 0; mi < MR; ++mi)
#pragma unroll
        for (int ni = 0; ni < 4; ++ni) acc[mi][ni] = (f32x4){0.f, 0.f, 0.f, 0.f};

    const int arow = tid >> 2;
    const int kq8 = (tid & 3) * 8;

    for (int k0 = kbeg; k0 < kend; k0 += 32) {
#pragma unroll
        for (int r = 0; r < BM / 64; ++r) {
            const short* srcA = A + (size_t)(m0 + r * 64 + arow) * K + (k0 + kq8);
            short* dstA = &A_lds[(r * 64 + wv * 16) * 32];
            __builtin_amdgcn_global_load_lds((const AS1 void*)srcA, (AS3 void*)dstA, 16, 0, 0);
        }
#pragma unroll
        for (int r = 0; r < 2; ++r) {
            int brow = n0 + r * 64 + arow;
            if (brow > N - 1) brow = N - 1;
            const short* srcB = B + (size_t)brow * K + (k0 + kq8);
            short* dstB = &B_lds[(r * 64 + wv * 16) * 32];
            __builtin_amdgcn_global_load_lds((const AS1 void*)srcB, (AS3 void*)dstB, 16, 0, 0);
        }
        __syncthreads();

        short8 av[MR], bv[4];
#pragma unroll
        for (int mi = 0; mi < MR; ++mi)
            av[mi] = *(const short8*)&A_lds[(wm * (BM / 2) + mi * 16 + lr) * 32 + kg * 8];
#pragma unroll
        for (int ni = 0; ni < 4; ++ni)
            bv[ni] = *(const short8*)&B_lds[(wn * 64 + ni * 16 + lr) * 32 + kg * 8];
#pragma unroll
        for (int mi = 0; mi < MR; ++mi)
#pragma unroll
            for (int ni = 0; ni < 4; ++ni)
                acc[mi][ni] = __builtin_amdgcn_mfma_f32_16x16x32_bf16(av[mi], bv[ni], acc[mi][ni], 0, 0, 0);
        __syncthreads();
    }

#pragma unroll
    for (int mi = 0; mi < MR; ++mi) {
        int crow0 = m0 + wm * (BM / 2) + mi * 16 + kg * 4;
#pragma unroll
        for (int ni = 0; ni < 4; ++ni) {
            int ccol = n0 + wn * 64 + ni * 16 + lr;
#pragma unroll
            for (int i = 0; i < 4; ++i) {
                float v = acc[mi][ni][i];
                size_t crow = (size_t)(crow0 + i);
                if constexpr (EPI == EPI_PLAIN) {
                    C[crow * ldc + ccol] = v;
                } else if constexpr (EPI == EPI_SPLIT) {
                    if (ccol < 4096) C[crow * 4096 + ccol] = v;
                    else C2[crow * 4096 + (ccol - 4096)] = v;
                } else if constexpr (EPI == EPI_ATOMIC) {
                    if (ccol < N) atomicAdd(&C[crow * ldc + ccol], v);
                } else {   // EPI_SOFTPLUS: bf16 softplus(v + bias[n]) -> dt
                    float x = v + bias[ccol];
                    float sp = fmaxf(x, 0.f) + log1pf(__expf(-fabsf(x)));
                    ((unsigned short*)C)[crow * ldc + ccol] = f2bf(sp);
                }
            }
        }
    }
}

// ================= chunked selective scan (bf16 dt/hc/gate) =================
#define CLEN 16
#define NCH 64

__global__ __launch_bounds__(256)
void scan_p1(const unsigned short* __restrict__ dt, const unsigned short* __restrict__ hc,
             const float* __restrict__ ssmp, const float* __restrict__ A_log,
             float* __restrict__ Sbuf, float* __restrict__ dtsum) {
    const int tid = threadIdx.x;
    const int c = blockIdx.x & (NCH - 1);
    const int db = blockIdx.x >> 6;
    const int d = db * 256 + tid;
    const int t0 = c * CLEN;

    float Ac[16];
#pragma unroll
    for (int i = 0; i < 4; ++i) {
        float4 v = *(const float4*)&A_log[d * 16 + i * 4];
        Ac[i*4+0] = -__expf(v.x); Ac[i*4+1] = -__expf(v.y);
        Ac[i*4+2] = -__expf(v.z); Ac[i*4+3] = -__expf(v.w);
    }

    __shared__ float sB[CLEN][16];
    sB[tid >> 4][tid & 15] = ssmp[(t0 + (tid >> 4)) * 160 + 128 + (tid & 15)];
    __syncthreads();

    float st[16];
#pragma unroll
    for (int n = 0; n < 16; ++n) st[n] = 0.f;
    float ds = 0.f;

    for (int tt = 0; tt < CLEN; ++tt) {
        size_t g = (size_t)(t0 + tt) * 4096 + d;
        float dtv = bf2f(dt[g]);
        float hcv = bf2f(hc[g]);
        float du = dtv * hcv;
        ds += dtv;
#pragma unroll
        for (int n = 0; n < 16; ++n) {
            float dA = __expf(dtv * Ac[n]);
            st[n] = fmaf(dA, st[n], du * sB[tt][n]);
        }
    }

    float* o = Sbuf + ((size_t)c * 4096 + d) * 16;
#pragma unroll
    for (int i = 0; i < 4; ++i)
        *(float4*)&o[i * 4] = make_float4(st[i*4], st[i*4+1], st[i*4+2], st[i*4+3]);
    dtsum[c * 4096 + d] = ds;
}

__global__ __launch_bounds__(256)
void scan_p2(const float* __restrict__ A_log, const float* __restrict__ dtsum,
             float* __restrict__ S) {
    const int idx = blockIdx.x * 256 + threadIdx.x;   // (d,n), 65536
    const int d = idx >> 4;
    const float Ac = -__expf(A_log[idx]);

    float sl[NCH], Pv[NCH];
#pragma unroll
    for (int c = 0; c < NCH; ++c) sl[c] = S[(size_t)c * 65536 + idx];
#pragma unroll
    for (int c = 0; c < NCH; ++c) Pv[c] = __expf(Ac * dtsum[c * 4096 + d]);

    float s = 0.f;
#pragma unroll
    for (int c = 0; c < NCH; ++c) {
        S[(size_t)c * 65536 + idx] = s;
        s = fmaf(Pv[c], s, sl[c]);
    }
}

__global__ __launch_bounds__(256)
void scan_p3(const unsigned short* __restrict__ dt, const unsigned short* __restrict__ hc,
             const float* __restrict__ ssmp, const float* __restrict__ A_log,
             const float* __restrict__ Dp, const unsigned short* __restrict__ gate,
             const float* __restrict__ Sinit, unsigned short* __restrict__ y_bf) {
    const int tid = threadIdx.x;
    const int c = blockIdx.x & (NCH - 1);
    const int db = blockIdx.x >> 6;
    const int d = db * 256 + tid;
    const int t0 = c * CLEN;

    float Ac[16];
#pragma unroll
    for (int i = 0; i < 4; ++i) {
        float4 v = *(const float4*)&A_log[d * 16 + i * 4];
        Ac[i*4+0] = -__expf(v.x); Ac[i*4+1] = -__expf(v.y);
        Ac[i*4+2] = -__expf(v.z); Ac[i*4+3] = -__expf(v.w);
    }
    const float Dcoef = Dp[d];

    __shared__ float sB[CLEN][16], sC[CLEN][16];
    {
        int tt = tid >> 4, nn = tid & 15;
        sB[tt][nn] = ssmp[(t0 + tt) * 160 + 128 + nn];
        sC[tt][nn] = ssmp[(t0 + tt) * 160 + 144 + nn];
    }
    __syncthreads();

    float st[16];
    {
        const float* si = Sinit + ((size_t)c * 4096 + d) * 16;
#pragma unroll
        for (int i = 0; i < 4; ++i) {
            float4 v = *(const float4*)&si[i * 4];
            st[i*4] = v.x; st[i*4+1] = v.y; st[i*4+2] = v.z; st[i*4+3] = v.w;
        }
    }

    for (int tt = 0; tt < CLEN; ++tt) {
        size_t g = (size_t)(t0 + tt) * 4096 + d;
        float dtv = bf2f(dt[g]);
        float hcv = bf2f(hc[g]);
        float du = dtv * hcv;
        float p[16];
#pragma unroll
        for (int n = 0; n < 16; ++n) {
            float dA = __expf(dtv * Ac[n]);
            st[n] = fmaf(dA, st[n], du * sB[tt][n]);
            p[n] = st[n] * sC[tt][n];
        }
#pragma unroll
        for (int n = 0; n < 8; ++n) p[n] += p[n + 8];
#pragma unroll
        for (int n = 0; n < 4; ++n) p[n] += p[n + 4];
        p[0] += p[2]; p[1] += p[3];
        float csum = p[0] + p[1];
        float gv = bf2f(gate[g]);   // already silu'd
        float yv = (csum + hcv * Dcoef) * gv;
        y_bf[g] = f2bf(yv);
    }
}

// ---------------- launch ----------------
extern "C" void kernel_launch(void* const* d_in, const int* in_sizes, int n_in,
                              void* d_out, int out_size, void* d_ws, size_t ws_size,
                              hipStream_t stream) {
    (void)in_sizes; (void)n_in; (void)out_size; (void)ws_size;
    const float* hidden = (const float*)d_in[0];
    const float* W_in   = (const float*)d_in[1];
    const float* conv_w = (const float*)d_in[2];
    const float* conv_b = (const float*)d_in[3];
    const float* W_x    = (const float*)d_in[4];
    const float* W_dt   = (const float*)d_in[5];
    const float* b_dt   = (const float*)d_in[6];
    const float* A_log  = (const float*)d_in[7];
    const float* D_p    = (const float*)d_in[8];
    const float* W_out  = (const float*)d_in[9];
    float* out = (float*)d_out;

    char* w = (char*)d_ws;
    unsigned short* hid_bf = (unsigned short*)w;  w += (size_t)1024 * 2048 * 2;
    unsigned short* Wbig   = (unsigned short*)w;  w += (size_t)8192 * 2048 * 2;
    unsigned short* h_bf   = (unsigned short*)w;  w += (size_t)1024 * 4096 * 2;
    unsigned short* gate_bf= (unsigned short*)w;  w += (size_t)1024 * 4096 * 2;
    // 32MB contiguous scratch: GEMM1 partials (2x16MB) and GEMM4 partials
    // (8x4MB); aliases hc_bf / dt_bf / Sbuf whose lifetimes don't overlap
    // the partial uses (partials die at reduce2; hc/dt/Sbuf die at scan_p3).
    unsigned short* pscr   = (unsigned short*)w;  w += (size_t)16 * 1024 * 1024 * 2;
    unsigned short* hc_bf  = pscr;                               // 8MB
    unsigned short* dt_bf  = pscr + (size_t)1024 * 4096;         // 8MB
    float* Sbuf            = (float*)(pscr + (size_t)2 * 1024 * 4096);  // 16MB
    float* ssmp            = (float*)w;           w += (size_t)1024 * 160 * 4;
    unsigned short* ts_bf  = (unsigned short*)w;  w += (size_t)1024 * 128 * 2;
    unsigned short* Wx_bf  = (unsigned short*)w;  w += (size_t)160 * 4096 * 2;
    unsigned short* Wdt_bf = (unsigned short*)w;  w += (size_t)4096 * 128 * 2;
    unsigned short* y_bf   = (unsigned short*)w;  w += (size_t)1024 * 4096 * 2;
    float* dtsum           = (float*)w;           w += (size_t)NCH * 4096 * 4;

    hipMemsetAsync(ssmp, 0, (size_t)1024 * 160 * 4, stream);   // GEMM2 atomic target

    cvt_f32_bf16<<<2048, 256, 0, stream>>>(hidden, hid_bf, 1024 * 2048 / 4);
    cvt_f32_bf16<<<4096, 256, 0, stream>>>(W_in, Wbig, 8192 * 2048 / 4);
    cvt_f32_bf16<<<640, 256, 0, stream>>>(W_x, Wx_bf, 160 * 4096 / 4);
    cvt_f32_bf16<<<512, 256, 0, stream>>>(W_dt, Wdt_bf, 4096 * 128 / 4);

    // GEMM1: proj = hidden @ W_in^T (256^2, split-K x2, bf16 partials)
    gemm256p<<<dim3(128, 1, 2), 512, 0, stream>>>(
        (const short*)hid_bf, (const short*)Wbig, pscr, 8192, 2048, 1024);
    // fused reduce + split: h bf16 | silu(gate) bf16
    reduce2<<<2048, 256, 0, stream>>>(pscr, h_bf, gate_bf);

    conv_silu<<<16384, 256, 0, stream>>>(h_bf, conv_w, conv_b, hc_bf);

    cvt_f32_bf16<<<2048, 256, 0, stream>>>(W_out, Wbig, 2048 * 4096 / 4);

    gemm_bt<128, EPI_ATOMIC><<<dim3(2, 8, 16), 256, 0, stream>>>(
        (const short*)hc_bf, (const short*)Wx_bf, ssmp, nullptr, nullptr,
        1024, 160, 4096, 160, 256);

    cvt_ts<<<128, 256, 0, stream>>>(ssmp, ts_bf);

    // GEMM3: dt = softplus(ts @ W_dt^T + b_dt) -> bf16
    gemm_bt<128, EPI_SOFTPLUS><<<dim3(32, 8, 1), 256, 0, stream>>>(
        (const short*)ts_bf, (const short*)Wdt_bf, (float*)dt_bf, nullptr, b_dt,
        1024, 4096, 128, 4096, 128);

    scan_p1<<<NCH * 16, 256, 0, stream>>>(dt_bf, hc_bf, ssmp, A_log, Sbuf, dtsum);
    scan_p2<<<256, 256, 0, stream>>>(A_log, dtsum, Sbuf);
    scan_p3<<<NCH * 16, 256, 0, stream>>>(dt_bf, hc_bf, ssmp, A_log, D_p, gate_bf, Sbuf, y_bf);

    // GEMM4: out = y @ W_out^T (256^2, split-K x8, bf16 partials) + reduce
    gemm256p<<<dim3(32, 1, 8), 512, 0, stream>>>(
        (const short*)y_bf, (const short*)Wbig, pscr, 2048, 4096, 512);
    reduce8<<<2048, 256, 0, stream>>>(pscr, out);
}

// Round 11
// 225.086 us; speedup vs baseline: 1.0301x; 1.0119x over previous
//
#include <hip/hip_runtime.h>
#include <math.h>

#define AS1 __attribute__((address_space(1)))
#define AS3 __attribute__((address_space(3)))

typedef __attribute__((ext_vector_type(8))) short short8;
typedef __attribute__((ext_vector_type(8))) unsigned short ushort8_t;
typedef __attribute__((ext_vector_type(4))) float f32x4;

#define WAITV(n) asm volatile("s_waitcnt vmcnt(" #n ")" ::: "memory")
#define BARRIER() asm volatile("s_barrier" ::: "memory")

static __device__ __forceinline__ unsigned short f2bf(float f) {
    unsigned u = __float_as_uint(f);
    unsigned r = (u + 0x7fffu + ((u >> 16) & 1u)) >> 16;
    return (unsigned short)r;
}
static __device__ __forceinline__ float bf2f(unsigned short u) {
    return __uint_as_float(((unsigned)u) << 16);
}

// ---------------- f32 -> bf16 convert (vectorized x4) ----------------
__global__ __launch_bounds__(256) void cvt_f32_bf16(const float* __restrict__ src,
                                                    unsigned short* __restrict__ dst,
                                                    int n4) {
    int i = blockIdx.x * 256 + threadIdx.x;
    int stride = gridDim.x * 256;
    for (; i < n4; i += stride) {
        float4 v = ((const float4*)src)[i];
        ushort4 o;
        o.x = f2bf(v.x); o.y = f2bf(v.y); o.z = f2bf(v.z); o.w = f2bf(v.w);
        ((ushort4*)dst)[i] = o;
    }
}

// extract ts (cols 0..127 of ssm_p, row stride 160) -> dense bf16 1024x128
__global__ __launch_bounds__(256) void cvt_ts(const float* __restrict__ ssmp,
                                              unsigned short* __restrict__ ts) {
    int i = blockIdx.x * 256 + threadIdx.x;   // < 32768
    int t = i >> 5, c4 = (i & 31) * 4;
    float4 v = *(const float4*)&ssmp[t * 160 + c4];
    ushort4 o;
    o.x = f2bf(v.x); o.y = f2bf(v.y); o.z = f2bf(v.z); o.w = f2bf(v.w);
    *(ushort4*)&ts[t * 128 + c4] = o;
}

// ------- depthwise causal conv (K=4, bf16 in) + bias + silu -> hc bf16 -------
__global__ __launch_bounds__(256) void conv_silu(const unsigned short* __restrict__ h,
                                                 const float* __restrict__ cw,
                                                 const float* __restrict__ cb,
                                                 unsigned short* __restrict__ hc_bf) {
    int idx = blockIdx.x * 256 + threadIdx.x;   // < 1024*4096
    int d = idx & 4095, t = idx >> 12;
    float acc = cb[d];
    float4 w = *(const float4*)&cw[d * 4];
    const float* wp = (const float*)&w;
#pragma unroll
    for (int k = 0; k < 4; ++k) {
        int tt = t + k - 3;
        if (tt >= 0) acc += bf2f(h[tt * 4096 + d]) * wp[k];
    }
    float s = acc / (1.f + __expf(-acc));   // silu
    hc_bf[idx] = f2bf(s);
}

// ---- reduce 2 bf16 split-K partials (1024x8192) -> h bf16 | silu(gate) bf16 ----
__global__ __launch_bounds__(256) void reduce2(const unsigned short* __restrict__ P,
                                               unsigned short* __restrict__ h_bf,
                                               unsigned short* __restrict__ gate_bf) {
    const int NCHK = 1024 * 8192 / 8;
    int i = blockIdx.x * 256 + threadIdx.x;
    int stride = gridDim.x * 256;
    for (; i < NCHK; i += stride) {
        ushort8_t a = ((const ushort8_t*)P)[i];
        ushort8_t b = ((const ushort8_t*)P)[i + NCHK];
        int e0 = i * 8;
        int row = e0 >> 13, col = e0 & 8191;
        ushort8_t o;
        if (col < 4096) {
#pragma unroll
            for (int j = 0; j < 8; ++j) o[j] = f2bf(bf2f(a[j]) + bf2f(b[j]));
            ((ushort8_t*)h_bf)[(row * 4096 + col) >> 3] = o;
        } else {
#pragma unroll
            for (int j = 0; j < 8; ++j) {
                float v = bf2f(a[j]) + bf2f(b[j]);
                o[j] = f2bf(v / (1.f + __expf(-v)));
            }
            ((ushort8_t*)gate_bf)[(row * 4096 + (col - 4096)) >> 3] = o;
        }
    }
}

// ---- reduce 8 bf16 split-K partials (1024x2048 each) -> f32 out ----
__global__ __launch_bounds__(256) void reduce8(const unsigned short* __restrict__ P,
                                               float* __restrict__ out) {
    const int NCHK = 1024 * 2048 / 4;
    int i = blockIdx.x * 256 + threadIdx.x;
    int stride = gridDim.x * 256;
    for (; i < NCHK; i += stride) {
        float4 s = make_float4(0.f, 0.f, 0.f, 0.f);
#pragma unroll
        for (int z = 0; z < 8; ++z) {
            ushort4 v = ((const ushort4*)(P + (size_t)z * 1024 * 2048))[i];
            s.x += bf2f(v.x); s.y += bf2f(v.y); s.z += bf2f(v.z); s.w += bf2f(v.w);
        }
        ((float4*)out)[i] = s;
    }
}

// ======== 256x256 quadrant-phase bf16 MFMA GEMM: C = A(M,K) @ B(N,K)^T ========
// BM=BN=256, BK=32. 512 threads = 8 waves (2M x 4N), wave tile 128x64.
// 3-buffer LDS (96KB), prefetch depth 2, counted vmcnt(4), 2 quadrant-phases
// per K-tile. LDS SWIZZLE (round-10 fix): the [256][32] bf16 row is 64B = 4
// 16B slots; unswizzled fragment reads hit 2 banks (8-way conflict, 3.1M
// measured). slot' = slot ^ ((row>>1)&3) -> read bank = 16(row&1) +
// 4*(kg^((row>>1)&3)) mod 32: 16 lanes spread over 8 banks x 2-way = free
// (m136). Applied both-sides (rule 21): linear LDS dest, global SOURCE slot
// pre-swizzled with the same involution; reads XOR the slot.
// XCD-bijective block swizzle. Split-K bf16 partials -> reduce2/reduce8.
__global__ __launch_bounds__(512, 2)
void gemm256p(const short* __restrict__ A, const short* __restrict__ B,
              unsigned short* __restrict__ Pbase,
              int N, int K, int kchunk) {
    __shared__ short lds[3 * 16384];   // per buf: A [256][32] (8192) + B [256][32]

    const int tid = threadIdx.x;
    const int wv = tid >> 6, ln = tid & 63;
    const int lr = ln & 15, kg = ln >> 4;
    const int wm = wv >> 2, wn = wv & 3;      // 2M x 4N

    const int nwg = gridDim.x;                 // multiple of 8
    const int bid = blockIdx.x;
    const int swz = (bid & 7) * (nwg >> 3) + (bid >> 3);
    const int by = swz & 3, bx = swz >> 2;     // M/256 = 4 always
    const int m0 = by * 256, n0 = bx * 256;
    const int kbeg = blockIdx.z * kchunk;
    const int NT = kchunk >> 5;                // BK = 32

    f32x4 acc[8][4];
#pragma unroll
    for (int mi = 0; mi < 8; ++mi)
#pragma unroll
        for (int ni = 0; ni < 4; ++ni) acc[mi][ni] = (f32x4){0.f, 0.f, 0.f, 0.f};

    const short* Abase = A + (size_t)m0 * K + kbeg;
    const short* Bbase = B + (size_t)n0 * K + kbeg;

// one staging pass: 512 threads x 16B = 128 rows of [256][32] bf16.
// LDS dest linear (wave-uniform base + lane*16B); global source slot
// pre-swizzled: LDS slot s of row r holds Global slot s ^ ((r>>1)&3).
#define STG(gbase, ldsoff, kt, b, pass)                                       \
    {                                                                         \
        int c = (pass) * 512 + tid;                                           \
        int row = c >> 2, s = c & 3;                                          \
        int ss = s ^ ((row >> 1) & 3);                                        \
        const short* src = (gbase) + (size_t)row * K + (kt) * 32 + ss * 8;    \
        short* dst = &lds[(b) * 16384 + (ldsoff) + ((pass) * 512 + wv * 64) * 8]; \
        __builtin_amdgcn_global_load_lds((const AS1 void*)src,                \
                                         (AS3 void*)dst, 16, 0, 0);           \
    }
#define STAGE_A(kt, b) { STG(Abase, 0, kt, b, 0); STG(Abase, 0, kt, b, 1); }
#define STAGE_B(kt, b) { STG(Bbase, 8192, kt, b, 0); STG(Bbase, 8192, kt, b, 1); }
#define RD_A(dst, mi)                                                         \
    { int row = wm * 128 + (mi) * 16 + lr;                                    \
      int s = kg ^ ((row >> 1) & 3);                                          \
      dst = *(const short8*)&la[row * 32 + s * 8]; }
#define RD_B(dst, ni)                                                         \
    { int row = wn * 64 + (ni) * 16 + lr;                                     \
      int s = kg ^ ((row >> 1) & 3);                                          \
      dst = *(const short8*)&lb[row * 32 + s * 8]; }
#define MFMA4(mi, a)                                                          \
    acc[mi][0] = __builtin_amdgcn_mfma_f32_16x16x32_bf16(a, vb0, acc[mi][0], 0, 0, 0); \
    acc[mi][1] = __builtin_amdgcn_mfma_f32_16x16x32_bf16(a, vb1, acc[mi][1], 0, 0, 0); \
    acc[mi][2] = __builtin_amdgcn_mfma_f32_16x16x32_bf16(a, vb2, acc[mi][2], 0, 0, 0); \
    acc[mi][3] = __builtin_amdgcn_mfma_f32_16x16x32_bf16(a, vb3, acc[mi][3], 0, 0, 0);

    // prologue: stage tiles 0 and 1 fully (4 loads each)
    STAGE_A(0, 0); STAGE_B(0, 0);
    STAGE_A(1, 1); STAGE_B(1, 1);

    int b = 0;
    for (int kt = 0; kt < NT; ++kt) {
        // drain exactly tile kt's 4 loads; tile kt+1's 4 stay in flight
        if (kt + 1 < NT) { WAITV(4); } else { WAITV(0); }
        BARRIER();   // tile kt staged & visible; all waves finished tile kt-1
        int bn = b + 2; if (bn >= 3) bn -= 3;    // == (kt-1)%3, freed by barrier
        if (kt + 2 < NT) STAGE_A(kt + 2, bn);

        const short* la = &lds[b * 16384];
        const short* lb = la + 8192;
        short8 va0, va1, va2, va3, vb0, vb1, vb2, vb3;
        // ---- phase 0: quadrant rows 0-63 of wave tile ----
        RD_B(vb0, 0); RD_B(vb1, 1); RD_B(vb2, 2); RD_B(vb3, 3);
        RD_A(va0, 0); RD_A(va1, 1); RD_A(va2, 2); RD_A(va3, 3);
        __builtin_amdgcn_s_setprio(1);
        MFMA4(0, va0); MFMA4(1, va1); MFMA4(2, va2); MFMA4(3, va3);
        __builtin_amdgcn_s_setprio(0);
        BARRIER();   // phase-lock: early waves' next reads drain under late MFMAs
        if (kt + 2 < NT) STAGE_B(kt + 2, bn);
        // ---- phase 1: quadrant rows 64-127 (B frags reused) ----
        RD_A(va0, 4); RD_A(va1, 5); RD_A(va2, 6); RD_A(va3, 7);
        __builtin_amdgcn_s_setprio(1);
        MFMA4(4, va0); MFMA4(5, va1); MFMA4(6, va2); MFMA4(7, va3);
        __builtin_amdgcn_s_setprio(0);
        b = (b + 1 == 3) ? 0 : b + 1;
    }
#undef STG
#undef STAGE_A
#undef STAGE_B
#undef RD_A
#undef RD_B
#undef MFMA4

    // epilogue: bf16 split-K partial, region z = blockIdx.z
    unsigned short* P = Pbase + (size_t)blockIdx.z * 1024 * N;
#pragma unroll
    for (int mi = 0; mi < 8; ++mi) {
        int crow0 = m0 + wm * 128 + mi * 16 + kg * 4;
#pragma unroll
        for (int ni = 0; ni < 4; ++ni) {
            int ccol = n0 + wn * 64 + ni * 16 + lr;
#pragma unroll
            for (int i = 0; i < 4; ++i)
                P[(size_t)(crow0 + i) * N + ccol] = f2bf(acc[mi][ni][i]);
        }
    }
}

// ---------------- 2-phase bf16 MFMA GEMM (GEMM2/3) ----------------
enum { EPI_PLAIN = 0, EPI_SPLIT = 1, EPI_ATOMIC = 2, EPI_SOFTPLUS = 3 };

template <int BM, int EPI>
__global__ __launch_bounds__(256)
void gemm_bt(const short* __restrict__ A, const short* __restrict__ B,
             float* __restrict__ C, float* __restrict__ C2,
             const float* __restrict__ bias,
             int M, int N, int K, int ldc, int kcLen) {
    __shared__ short A_lds[BM * 32];
    __shared__ short B_lds[128 * 32];
    const int tid = threadIdx.x;
    const int wv = tid >> 6, ln = tid & 63;
    const int lr = ln & 15, kg = ln >> 4;
    const int m0 = blockIdx.y * BM;
    const int n0 = blockIdx.x * 128;
    const int kbeg = blockIdx.z * kcLen;
    const int kend = kbeg + kcLen;
    const int wm = wv >> 1, wn = wv & 1;
    constexpr int MR = BM / 32;

    f32x4 acc[MR][4];
#pragma unroll
    for (int mi = 0; mi < MR; ++mi)
#pragma unroll
        for (int ni = 0; ni < 4; ++ni) acc[mi][ni] = (f32x4){0.f, 0.f, 0.f, 0.f};

    const int arow = tid >> 2;
    const int kq8 = (tid & 3) * 8;

    for (int k0 = kbeg; k0 < kend; k0 += 32) {
#pragma unroll
        for (int r = 0; r < BM / 64; ++r) {
            const short* srcA = A + (size_t)(m0 + r * 64 + arow) * K + (k0 + kq8);
            short* dstA = &A_lds[(r * 64 + wv * 16) * 32];
            __builtin_amdgcn_global_load_lds((const AS1 void*)srcA, (AS3 void*)dstA, 16, 0, 0);
        }
#pragma unroll
        for (int r = 0; r < 2; ++r) {
            int brow = n0 + r * 64 + arow;
            if (brow > N - 1) brow = N - 1;
            const short* srcB = B + (size_t)brow * K + (k0 + kq8);
            short* dstB = &B_lds[(r * 64 + wv * 16) * 32];
            __builtin_amdgcn_global_load_lds((const AS1 void*)srcB, (AS3 void*)dstB, 16, 0, 0);
        }
        __syncthreads();

        short8 av[MR], bv[4];
#pragma unroll
        for (int mi = 0; mi < MR; ++mi)
            av[mi] = *(const short8*)&A_lds[(wm * (BM / 2) + mi * 16 + lr) * 32 + kg * 8];
#pragma unroll
        for (int ni = 0; ni < 4; ++ni)
            bv[ni] = *(const short8*)&B_lds[(wn * 64 + ni * 16 + lr) * 32 + kg * 8];
#pragma unroll
        for (int mi = 0; mi < MR; ++mi)
#pragma unroll
            for (int ni = 0; ni < 4; ++ni)
                acc[mi][ni] = __builtin_amdgcn_mfma_f32_16x16x32_bf16(av[mi], bv[ni], acc[mi][ni], 0, 0, 0);
        __syncthreads();
    }

#pragma unroll
    for (int mi = 0; mi < MR; ++mi) {
        int crow0 = m0 + wm * (BM / 2) + mi * 16 + kg * 4;
#pragma unroll
        for (int ni = 0; ni < 4; ++ni) {
            int ccol = n0 + wn * 64 + ni * 16 + lr;
#pragma unroll
            for (int i = 0; i < 4; ++i) {
                float v = acc[mi][ni][i];
                size_t crow = (size_t)(crow0 + i);
                if constexpr (EPI == EPI_PLAIN) {
                    C[crow * ldc + ccol] = v;
                } else if constexpr (EPI == EPI_SPLIT) {
                    if (ccol < 4096) C[crow * 4096 + ccol] = v;
                    else C2[crow * 4096 + (ccol - 4096)] = v;
                } else if constexpr (EPI == EPI_ATOMIC) {
                    if (ccol < N) atomicAdd(&C[crow * ldc + ccol], v);
                } else {   // EPI_SOFTPLUS: bf16 softplus(v + bias[n]) -> dt
                    float x = v + bias[ccol];
                    float sp = fmaxf(x, 0.f) + log1pf(__expf(-fabsf(x)));
                    ((unsigned short*)C)[crow * ldc + ccol] = f2bf(sp);
                }
            }
        }
    }
}

// ================= chunked selective scan (bf16 dt/hc/gate) =================
#define CLEN 16
#define NCH 64

__global__ __launch_bounds__(256)
void scan_p1(const unsigned short* __restrict__ dt, const unsigned short* __restrict__ hc,
             const float* __restrict__ ssmp, const float* __restrict__ A_log,
             float* __restrict__ Sbuf, float* __restrict__ dtsum) {
    const int tid = threadIdx.x;
    const int c = blockIdx.x & (NCH - 1);
    const int db = blockIdx.x >> 6;
    const int d = db * 256 + tid;
    const int t0 = c * CLEN;

    float Ac[16];
#pragma unroll
    for (int i = 0; i < 4; ++i) {
        float4 v = *(const float4*)&A_log[d * 16 + i * 4];
        Ac[i*4+0] = -__expf(v.x); Ac[i*4+1] = -__expf(v.y);
        Ac[i*4+2] = -__expf(v.z); Ac[i*4+3] = -__expf(v.w);
    }

    __shared__ float sB[CLEN][16];
    sB[tid >> 4][tid & 15] = ssmp[(t0 + (tid >> 4)) * 160 + 128 + (tid & 15)];
    __syncthreads();

    float st[16];
#pragma unroll
    for (int n = 0; n < 16; ++n) st[n] = 0.f;
    float ds = 0.f;

    for (int tt = 0; tt < CLEN; ++tt) {
        size_t g = (size_t)(t0 + tt) * 4096 + d;
        float dtv = bf2f(dt[g]);
        float hcv = bf2f(hc[g]);
        float du = dtv * hcv;
        ds += dtv;
#pragma unroll
        for (int n = 0; n < 16; ++n) {
            float dA = __expf(dtv * Ac[n]);
            st[n] = fmaf(dA, st[n], du * sB[tt][n]);
        }
    }

    float* o = Sbuf + ((size_t)c * 4096 + d) * 16;
#pragma unroll
    for (int i = 0; i < 4; ++i)
        *(float4*)&o[i * 4] = make_float4(st[i*4], st[i*4+1], st[i*4+2], st[i*4+3]);
    dtsum[c * 4096 + d] = ds;
}

__global__ __launch_bounds__(256)
void scan_p2(const float* __restrict__ A_log, const float* __restrict__ dtsum,
             float* __restrict__ S) {
    const int idx = blockIdx.x * 256 + threadIdx.x;   // (d,n), 65536
    const int d = idx >> 4;
    const float Ac = -__expf(A_log[idx]);

    float sl[NCH], Pv[NCH];
#pragma unroll
    for (int c = 0; c < NCH; ++c) sl[c] = S[(size_t)c * 65536 + idx];
#pragma unroll
    for (int c = 0; c < NCH; ++c) Pv[c] = __expf(Ac * dtsum[c * 4096 + d]);

    float s = 0.f;
#pragma unroll
    for (int c = 0; c < NCH; ++c) {
        S[(size_t)c * 65536 + idx] = s;
        s = fmaf(Pv[c], s, sl[c]);
    }
}

__global__ __launch_bounds__(256)
void scan_p3(const unsigned short* __restrict__ dt, const unsigned short* __restrict__ hc,
             const float* __restrict__ ssmp, const float* __restrict__ A_log,
             const float* __restrict__ Dp, const unsigned short* __restrict__ gate,
             const float* __restrict__ Sinit, unsigned short* __restrict__ y_bf) {
    const int tid = threadIdx.x;
    const int c = blockIdx.x & (NCH - 1);
    const int db = blockIdx.x >> 6;
    const int d = db * 256 + tid;
    const int t0 = c * CLEN;

    float Ac[16];
#pragma unroll
    for (int i = 0; i < 4; ++i) {
        float4 v = *(const float4*)&A_log[d * 16 + i * 4];
        Ac[i*4+0] = -__expf(v.x); Ac[i*4+1] = -__expf(v.y);
        Ac[i*4+2] = -__expf(v.z); Ac[i*4+3] = -__expf(v.w);
    }
    const float Dcoef = Dp[d];

    __shared__ float sB[CLEN][16], sC[CLEN][16];
    {
        int tt = tid >> 4, nn = tid & 15;
        sB[tt][nn] = ssmp[(t0 + tt) * 160 + 128 + nn];
        sC[tt][nn] = ssmp[(t0 + tt) * 160 + 144 + nn];
    }
    __syncthreads();

    float st[16];
    {
        const float* si = Sinit + ((size_t)c * 4096 + d) * 16;
#pragma unroll
        for (int i = 0; i < 4; ++i) {
            float4 v = *(const float4*)&si[i * 4];
            st[i*4] = v.x; st[i*4+1] = v.y; st[i*4+2] = v.z; st[i*4+3] = v.w;
        }
    }

    for (int tt = 0; tt < CLEN; ++tt) {
        size_t g = (size_t)(t0 + tt) * 4096 + d;
        float dtv = bf2f(dt[g]);
        float hcv = bf2f(hc[g]);
        float du = dtv * hcv;
        float p[16];
#pragma unroll
        for (int n = 0; n < 16; ++n) {
            float dA = __expf(dtv * Ac[n]);
            st[n] = fmaf(dA, st[n], du * sB[tt][n]);
            p[n] = st[n] * sC[tt][n];
        }
#pragma unroll
        for (int n = 0; n < 8; ++n) p[n] += p[n + 8];
#pragma unroll
        for (int n = 0; n < 4; ++n) p[n] += p[n + 4];
        p[0] += p[2]; p[1] += p[3];
        float csum = p[0] + p[1];
        float gv = bf2f(gate[g]);   // already silu'd
        float yv = (csum + hcv * Dcoef) * gv;
        y_bf[g] = f2bf(yv);
    }
}

// ---------------- launch ----------------
extern "C" void kernel_launch(void* const* d_in, const int* in_sizes, int n_in,
                              void* d_out, int out_size, void* d_ws, size_t ws_size,
                              hipStream_t stream) {
    (void)in_sizes; (void)n_in; (void)out_size; (void)ws_size;
    const float* hidden = (const float*)d_in[0];
    const float* W_in   = (const float*)d_in[1];
    const float* conv_w = (const float*)d_in[2];
    const float* conv_b = (const float*)d_in[3];
    const float* W_x    = (const float*)d_in[4];
    const float* W_dt   = (const float*)d_in[5];
    const float* b_dt   = (const float*)d_in[6];
    const float* A_log  = (const float*)d_in[7];
    const float* D_p    = (const float*)d_in[8];
    const float* W_out  = (const float*)d_in[9];
    float* out = (float*)d_out;

    char* w = (char*)d_ws;
    unsigned short* hid_bf = (unsigned short*)w;  w += (size_t)1024 * 2048 * 2;
    unsigned short* Wbig   = (unsigned short*)w;  w += (size_t)8192 * 2048 * 2;
    unsigned short* h_bf   = (unsigned short*)w;  w += (size_t)1024 * 4096 * 2;
    unsigned short* gate_bf= (unsigned short*)w;  w += (size_t)1024 * 4096 * 2;
    // 32MB contiguous scratch: GEMM1 partials (2x16MB) and GEMM4 partials
    // (8x4MB); aliases hc_bf / dt_bf / Sbuf whose lifetimes don't overlap
    // the partial uses (partials die at reduce2; hc/dt/Sbuf die at scan_p3).
    unsigned short* pscr   = (unsigned short*)w;  w += (size_t)16 * 1024 * 1024 * 2;
    unsigned short* hc_bf  = pscr;                               // 8MB
    unsigned short* dt_bf  = pscr + (size_t)1024 * 4096;         // 8MB
    float* Sbuf            = (float*)(pscr + (size_t)2 * 1024 * 4096);  // 16MB
    float* ssmp            = (float*)w;           w += (size_t)1024 * 160 * 4;
    unsigned short* ts_bf  = (unsigned short*)w;  w += (size_t)1024 * 128 * 2;
    unsigned short* Wx_bf  = (unsigned short*)w;  w += (size_t)160 * 4096 * 2;
    unsigned short* Wdt_bf = (unsigned short*)w;  w += (size_t)4096 * 128 * 2;
    unsigned short* y_bf   = (unsigned short*)w;  w += (size_t)1024 * 4096 * 2;
    float* dtsum           = (float*)w;           w += (size_t)NCH * 4096 * 4;

    hipMemsetAsync(ssmp, 0, (size_t)1024 * 160 * 4, stream);   // GEMM2 atomic target

    cvt_f32_bf16<<<2048, 256, 0, stream>>>(hidden, hid_bf, 1024 * 2048 / 4);
    cvt_f32_bf16<<<4096, 256, 0, stream>>>(W_in, Wbig, 8192 * 2048 / 4);
    cvt_f32_bf16<<<640, 256, 0, stream>>>(W_x, Wx_bf, 160 * 4096 / 4);
    cvt_f32_bf16<<<512, 256, 0, stream>>>(W_dt, Wdt_bf, 4096 * 128 / 4);

    // GEMM1: proj = hidden @ W_in^T (256^2, split-K x2, bf16 partials)
    gemm256p<<<dim3(128, 1, 2), 512, 0, stream>>>(
        (const short*)hid_bf, (const short*)Wbig, pscr, 8192, 2048, 1024);
    // fused reduce + split: h bf16 | silu(gate) bf16
    reduce2<<<2048, 256, 0, stream>>>(pscr, h_bf, gate_bf);

    conv_silu<<<16384, 256, 0, stream>>>(h_bf, conv_w, conv_b, hc_bf);

    cvt_f32_bf16<<<2048, 256, 0, stream>>>(W_out, Wbig, 2048 * 4096 / 4);

    gemm_bt<128, EPI_ATOMIC><<<dim3(2, 8, 16), 256, 0, stream>>>(
        (const short*)hc_bf, (const short*)Wx_bf, ssmp, nullptr, nullptr,
        1024, 160, 4096, 160, 256);

    cvt_ts<<<128, 256, 0, stream>>>(ssmp, ts_bf);

    // GEMM3: dt = softplus(ts @ W_dt^T + b_dt) -> bf16
    gemm_bt<128, EPI_SOFTPLUS><<<dim3(32, 8, 1), 256, 0, stream>>>(
        (const short*)ts_bf, (const short*)Wdt_bf, (float*)dt_bf, nullptr, b_dt,
        1024, 4096, 128, 4096, 128);

    scan_p1<<<NCH * 16, 256, 0, stream>>>(dt_bf, hc_bf, ssmp, A_log, Sbuf, dtsum);
    scan_p2<<<256, 256, 0, stream>>>(A_log, dtsum, Sbuf);
    scan_p3<<<NCH * 16, 256, 0, stream>>>(dt_bf, hc_bf, ssmp, A_log, D_p, gate_bf, Sbuf, y_bf);

    // GEMM4: out = y @ W_out^T (256^2, split-K x8, bf16 partials) + reduce
    gemm256p<<<dim3(32, 1, 8), 512, 0, stream>>>(
        (const short*)y_bf, (const short*)Wbig, pscr, 2048, 4096, 512);
    reduce8<<<2048, 256, 0, stream>>>(pscr, out);
}